// Round 10
// baseline (46.916 us; speedup 1.0000x reference)
//
#include <hip/hip_runtime.h>

#define NQ    12
#define BATCH 8192

typedef float v2f __attribute__((ext_vector_type(2)));

// ---------------------------------------------------------------------------
// One wave = one batch element's 4096-dim real state (imag identically 0).
// Layout A: lane bits = qubits 6..11, reg bits = qubits 0..5
// Layout B: lane bits = qubits 0..5,  reg bits = qubits 6..11
// Per layer: 6 reg-gates, LDS transpose, 6 reg-gates, ring boundary CNOTs;
// ring renamings (sig powers) deferred via compile-time index renaming.
// RY in tan form (G = prod cos folded into epilogue as G^2); state float2[32],
// gates via v_pk_fma_f32.
// Transpose pair-slot layout: slot(r,rho) = (r>>1)*66 + 2*rho + (r&1) words.
//   S=66 (== 2 mod 64): no aliasing (round-9's S=34 aliased!), b64 writes at
//   word k*66+2rho (banks 2-way min), read2_b32 at base (j>>1)*66+(j&1) with
//   dword offsets {4k, 4k+2} (banks exactly 2 lanes/bank). LDS 16896 B/block.
// ---------------------------------------------------------------------------

constexpr int sig6(int x)            { return (x ^ (x << 1)) & 63; }
constexpr int sigpow6(int x, int t)  { return t == 0 ? x : sigpow6(sig6(x), t - 1); }
constexpr int rowmask6(int j, int t) {        // bit_j(sig^-t(p)) = par(p & m)
    int tt = (8 - (t % 8)) % 8;
    int m = 0;
    for (int i = 0; i < 6; ++i)
        if ((sigpow6(1 << i, tt) >> j) & 1) m |= 1 << i;
    return m;
}
constexpr bool par6(int x) { return (__builtin_popcount(x & 63) & 1) != 0; }

#define VAT(w, i) w[(i) >> 1][(i) & 1]

// ---- cross-lane helpers ---------------------------------------------------
template<int C>
__device__ __forceinline__ float dppf(float x) {
    return __int_as_float(__builtin_amdgcn_mov_dpp(__float_as_int(x), C, 0xF, 0xF, true));
}

template<int M>
__device__ __forceinline__ float shx(float x) {
    static_assert(M > 0 && M < 64, "mask");
    constexpr int lo = M & 31;
    float y = x;
    if constexpr (lo == 1)       y = dppf<0xB1>(y);
    else if constexpr (lo == 2)  y = dppf<0x4E>(y);
    else if constexpr (lo == 3)  y = dppf<0x1B>(y);
    else if constexpr (lo == 7)  y = dppf<0x141>(y);
    else if constexpr (lo == 15) y = dppf<0x140>(y);
    else if constexpr (lo != 0)
        y = __int_as_float(__builtin_amdgcn_ds_swizzle(__float_as_int(y),
                                                       0x1F | (lo << 10)));
    if constexpr ((M & 32) != 0) {
        int yi = __float_as_int(y);
        auto p = __builtin_amdgcn_permlane32_swap(yi, yi, false, false);
        y = (__int_as_float(p[0]) + __int_as_float(p[1])) - y;
    }
    return y;
}

// signed butterfly: returns sum_l (-1)^par(l&M) x_l (writing lanes 0..11 all
// sign-positive).
template<int M>
__device__ __forceinline__ float wave_red(float x) {
    { float o = dppf<0xB1>(x); x = (M & 1)  ? x - o : x + o; }
    { float o = dppf<0x4E>(x); x = (M & 2)  ? x - o : x + o; }
    { float o = __int_as_float(__builtin_amdgcn_ds_swizzle(__float_as_int(x), 0x1F | (4  << 10))); x = (M & 4)  ? x - o : x + o; }
    { float o = __int_as_float(__builtin_amdgcn_ds_swizzle(__float_as_int(x), 0x1F | (8  << 10))); x = (M & 8)  ? x - o : x + o; }
    { float o = __int_as_float(__builtin_amdgcn_ds_swizzle(__float_as_int(x), 0x1F | (16 << 10))); x = (M & 16) ? x - o : x + o; }
    int xi = __float_as_int(x);
    auto p = __builtin_amdgcn_permlane32_swap(xi, xi, false, false);
    float s = __int_as_float(p[0]) + __int_as_float(p[1]);
    return (M & 32) ? (2.0f * x - s) : s;
}

// ---- packed tan-form RY on reg qubit-bit Q, renaming sig^T ----------------
template<int T, int Q>
__device__ __forceinline__ void regRY(v2f* w, float t) {
    constexpr int D = sigpow6(1 << Q, T);   // physical partner xor
    const v2f tMM = {-t, -t}, tPP = {t, t}, tMP = {-t, t}, tPM = {t, -t};
    if constexpr (Q == 0) {
        constexpr int K = D >> 1;           // D odd: comp-swapped partner
        #pragma unroll
        for (int k = 0; k < 32; ++k) {
            const int k2 = k ^ K;
            if (k2 < k) continue;
            v2f a = w[k], b = w[k2];
            v2f sb = {b[1], b[0]}, sa = {a[1], a[0]};
            w[k]  = __builtin_elementwise_fma(tMP, sb, a);
            w[k2] = __builtin_elementwise_fma(tMP, sa, b);
        }
    } else {
        constexpr int K  = D >> 1;          // D even: comps aligned
        constexpr int RM = rowmask6(Q, T);
        #pragma unroll
        for (int k = 0; k < 32; ++k) {
            const int k2 = k ^ K;
            if (k2 < k) continue;
            const bool p = par6((2 * k) & RM);
            if constexpr (RM & 1) {
                v2f a = w[k], b = w[k2];
                const v2f tk  = p ? tPM : tMP;
                const v2f tk2 = p ? tMP : tPM;
                w[k]  = __builtin_elementwise_fma(tk,  b, a);
                w[k2] = __builtin_elementwise_fma(tk2, a, b);
            } else {
                if (p) {
                    v2f a = w[k2], b = w[k];
                    w[k2] = __builtin_elementwise_fma(tMM, b, a);
                    w[k]  = __builtin_elementwise_fma(tPP, a, b);
                } else {
                    v2f a = w[k], b = w[k2];
                    w[k]  = __builtin_elementwise_fma(tMM, b, a);
                    w[k2] = __builtin_elementwise_fma(tPP, a, b);
                }
            }
        }
    }
}

// ---- ring boundary CNOTs --------------------------------------------------
template<int T>          // layout A CNOT(5,6): reg bit5 controls lane xor
__device__ __forceinline__ void c56A(v2f* w) {
    constexpr int ML = sigpow6(1, T);
    #pragma unroll
    for (int r = 32; r < 64; ++r) {
        const int pr = sigpow6(r, T + 1);
        VAT(w, pr) = shx<ML>(VAT(w, pr));
    }
}
template<int T>          // layout A CNOT(11,0): lane bit5 controls reg swap
__device__ __forceinline__ void c110A(v2f* w, int lane) {
    const bool cond = par6(lane & rowmask6(5, T + 1));
    constexpr int D = sigpow6(1, T + 1);
    #pragma unroll
    for (int r0 = 0; r0 < 64; r0 += 2) {
        const int a0 = sigpow6(r0, T + 1);
        const int a1 = a0 ^ D;
        float x0 = VAT(w, a0), x1 = VAT(w, a1);
        VAT(w, a0) = cond ? x1 : x0;
        VAT(w, a1) = cond ? x0 : x1;
    }
}
template<int T>          // layout B CNOT(5,6): lane bit5 controls reg swap
__device__ __forceinline__ void c56B(v2f* w, int lane) {
    const bool cond = par6(lane & rowmask6(5, T + 1));
    constexpr int D = sigpow6(1, T);
    #pragma unroll
    for (int r0 = 0; r0 < 64; r0 += 2) {
        const int a0 = sigpow6(r0, T);
        const int a1 = a0 ^ D;
        float x0 = VAT(w, a0), x1 = VAT(w, a1);
        VAT(w, a0) = cond ? x1 : x0;
        VAT(w, a1) = cond ? x0 : x1;
    }
}
template<int T>          // layout B CNOT(11,0): reg bit5 controls lane xor
__device__ __forceinline__ void c110B(v2f* w) {
    constexpr int ML = sigpow6(1, T + 1);
    #pragma unroll
    for (int r = 32; r < 64; ++r) {
        const int pr = sigpow6(r, T + 1);
        VAT(w, pr) = shx<ML>(VAT(w, pr));
    }
}
template<int T>
__device__ __forceinline__ void ringA(v2f* w, int lane) { c56A<T>(w); c110A<T>(w, lane); }
template<int T>
__device__ __forceinline__ void ringB(v2f* w, int lane) { c56B<T>(w, lane); c110B<T>(w); }

// ---- lane<->reg transpose, 2-phase, pair-slot layout (S = 66) -------------
// slot(r, rho) = (r>>1)*66 + 2*rho + (r&1) words.  Phase 1: writer lanes
// 0..31 (rho = lane) emit 32 ds_write_b64 of natural v2f pairs at word
// k*66 + 2*rho; readers (all lanes j) fetch new reg pair (2k,2k+1) =
// slots (r=j, rho=2k / 2k+1) via ds_read2_b32 at base (j>>1)*66 + (j&1),
// dword offsets {4k, 4k+2}.  Phase 2 same with writer lanes 32..63 and
// regs 32..63.  Same-wave DS ops are processed in order -> no barrier.
__device__ __forceinline__ void transpose64(v2f* w, float* sh, int lane) {
    const int row = lane & 31;
    const int rm  = (lane >> 1) * 66 + (lane & 1);
    v2f nv[16];
    if (lane < 32) {
        #pragma unroll
        for (int k = 0; k < 32; ++k)
            *reinterpret_cast<v2f*>(sh + row * 2 + k * 66) = w[k];
    }
    asm volatile("" ::: "memory");
    #pragma unroll
    for (int k = 0; k < 16; ++k) {
        nv[k][0] = sh[rm + 4 * k];
        nv[k][1] = sh[rm + 4 * k + 2];
    }
    asm volatile("" ::: "memory");
    if (lane >= 32) {
        #pragma unroll
        for (int k = 0; k < 32; ++k)
            *reinterpret_cast<v2f*>(sh + row * 2 + k * 66) = w[k];
    }
    asm volatile("" ::: "memory");
    #pragma unroll
    for (int k = 0; k < 16; ++k) {
        w[16 + k][0] = sh[rm + 4 * k];
        w[16 + k][1] = sh[rm + 4 * k + 2];
    }
    #pragma unroll
    for (int k = 0; k < 16; ++k) w[k] = nv[k];
    asm volatile("" ::: "memory");
}

__device__ __forceinline__ float tanhalf(float ang, float& G) {
    float s, c;
    __sincosf(ang, &s, &c);
    G *= c;
    return s * __builtin_amdgcn_rcpf(c);
}

// layer entering in layout A (theta row T; ends in layout B)
template<int T>
__device__ __forceinline__ void layerA(v2f* w, const float* __restrict__ th,
                                       int lane, float& G, float* sh) {
    regRY<T, 0>(w, tanhalf(0.5f * th[T * NQ + 0], G));
    regRY<T, 1>(w, tanhalf(0.5f * th[T * NQ + 1], G));
    regRY<T, 2>(w, tanhalf(0.5f * th[T * NQ + 2], G));
    regRY<T, 3>(w, tanhalf(0.5f * th[T * NQ + 3], G));
    regRY<T, 4>(w, tanhalf(0.5f * th[T * NQ + 4], G));
    regRY<T, 5>(w, tanhalf(0.5f * th[T * NQ + 5], G));
    transpose64(w, sh, lane);
    regRY<T, 0>(w, tanhalf(0.5f * th[T * NQ + 6],  G));
    regRY<T, 1>(w, tanhalf(0.5f * th[T * NQ + 7],  G));
    regRY<T, 2>(w, tanhalf(0.5f * th[T * NQ + 8],  G));
    regRY<T, 3>(w, tanhalf(0.5f * th[T * NQ + 9],  G));
    regRY<T, 4>(w, tanhalf(0.5f * th[T * NQ + 10], G));
    regRY<T, 5>(w, tanhalf(0.5f * th[T * NQ + 11], G));
    ringB<T>(w, lane);
}

// layer entering in layout B (theta row T; ends in layout A)
template<int T>
__device__ __forceinline__ void layerB(v2f* w, const float* __restrict__ th,
                                       int lane, float& G, float* sh) {
    regRY<T, 0>(w, tanhalf(0.5f * th[T * NQ + 6],  G));
    regRY<T, 1>(w, tanhalf(0.5f * th[T * NQ + 7],  G));
    regRY<T, 2>(w, tanhalf(0.5f * th[T * NQ + 8],  G));
    regRY<T, 3>(w, tanhalf(0.5f * th[T * NQ + 9],  G));
    regRY<T, 4>(w, tanhalf(0.5f * th[T * NQ + 10], G));
    regRY<T, 5>(w, tanhalf(0.5f * th[T * NQ + 11], G));
    transpose64(w, sh, lane);
    regRY<T, 0>(w, tanhalf(0.5f * th[T * NQ + 0], G));
    regRY<T, 1>(w, tanhalf(0.5f * th[T * NQ + 1], G));
    regRY<T, 2>(w, tanhalf(0.5f * th[T * NQ + 2], G));
    regRY<T, 3>(w, tanhalf(0.5f * th[T * NQ + 3], G));
    regRY<T, 4>(w, tanhalf(0.5f * th[T * NQ + 4], G));
    regRY<T, 5>(w, tanhalf(0.5f * th[T * NQ + 5], G));
    ringA<T>(w, lane);
}

__global__ __launch_bounds__(128)
void qc_kernel(const float* __restrict__ x, const float* __restrict__ theta,
               float* __restrict__ out) {
    __shared__ float shbuf[2][2112];   // max slot 31*66+63 = 2109
    const int lane = threadIdx.x & 63;
    const int wid  = threadIdx.x >> 6;
    const int b = __builtin_amdgcn_readfirstlane((blockIdx.x << 1) + wid);
    float* sh = &shbuf[wid][0];

    alignas(16) v2f w[32];

    // ---- init in layout A, layer-0 thetas folded: RY(th)RY(x)|0> = RY(x+th)|0>
    float L = 1.0f;
    #pragma unroll
    for (int q = 6; q < NQ; ++q) {
        float s, c;
        __sincosf(0.5f * (x[b * NQ + q] + theta[q]), &s, &c);
        L *= ((lane >> (q - 6)) & 1) ? s : c;
    }
    {
        float s, c;
        __sincosf(0.5f * (x[b * NQ + 0] + theta[0]), &s, &c);
        w[0] = {L * c, L * s};
    }
    #pragma unroll
    for (int q = 1; q < 6; ++q) {
        float s, c;
        __sincosf(0.5f * (x[b * NQ + q] + theta[q]), &s, &c);
        const v2f vs = {s, s}, vc = {c, c};
        #pragma unroll
        for (int k = 0; k < (1 << (q - 1)); ++k) {
            w[k + (1 << (q - 1))] = w[k] * vs;
            w[k]                  = w[k] * vc;
        }
    }

    float G = 1.0f;            // product of cosines over layers 1..3
    ringA<0>(w, lane);         // layer-0 ring (gates folded into init)
    layerA<1>(w, theta, lane, G, sh);   // A -> B
    layerB<2>(w, theta, lane, G, sh);   // B -> A
    layerA<3>(w, theta, lane, G, sh);   // A -> B
    // final: layout B, renaming powers (4,4)

    // ---- epilogue: out[b,q] = G^2 * sum_d v^2 * (1-2 bit_q(d))
    // phys = sig^4(L): L0..3 = phys0..3, L4 = phys4^phys0, L5 = phys5^phys1.
    // comp = phys bit0; w-index bits = phys bits 1..5.  Packed 5-level tree.
    #pragma unroll
    for (int k = 0; k < 32; ++k) w[k] = w[k] * w[k];

    v2f u1[16], c1[16];
    #pragma unroll
    for (int m = 0; m < 16; ++m) {
        u1[m] = w[2 * m] + w[2 * m + 1];
        c1[m] = w[2 * m] - w[2 * m + 1];     // sign: phys1
    }
    v2f u2[8], d2v = {0.f, 0.f};
    #pragma unroll
    for (int m = 0; m < 8; ++m) {
        u2[m] = u1[2 * m] + u1[2 * m + 1];
        d2v  += u1[2 * m] - u1[2 * m + 1];   // sign: phys2
    }
    v2f c2[8];
    #pragma unroll
    for (int m = 0; m < 8; ++m) c2[m] = c1[2 * m] + c1[2 * m + 1];
    v2f u3[4], d3v = {0.f, 0.f};
    #pragma unroll
    for (int m = 0; m < 4; ++m) {
        u3[m] = u2[2 * m] + u2[2 * m + 1];
        d3v  += u2[2 * m] - u2[2 * m + 1];   // sign: phys3
    }
    v2f c3[4];
    #pragma unroll
    for (int m = 0; m < 4; ++m) c3[m] = c2[2 * m] + c2[2 * m + 1];
    v2f u4[2], c4[2];
    u4[0] = u3[0] + u3[1]; u4[1] = u3[2] + u3[3];
    v2f d4v = (u3[0] - u3[1]) + (u3[2] - u3[3]);   // sign: phys4
    c4[0] = c3[0] + c3[1]; c4[1] = c3[2] + c3[3];
    v2f U  = u4[0] + u4[1];
    v2f cS = c4[0] + c4[1];                  // sign: phys1
    v2f cD = c4[0] - c4[1];                  // sign: phys1^phys5

    const float tot = U[0] + U[1];
    float Dq[6];
    Dq[0] = U[0] - U[1];
    Dq[1] = cS[0] + cS[1];
    Dq[2] = d2v[0] + d2v[1];
    Dq[3] = d3v[0] + d3v[1];
    Dq[4] = d4v[0] - d4v[1];                 // ^phys0 via comp sign
    Dq[5] = cD[0] + cD[1];

    float res[NQ];
    res[0] = wave_red<rowmask6(0, 4)>(tot);  // lane qubits 0..5
    res[1] = wave_red<rowmask6(1, 4)>(tot);
    res[2] = wave_red<rowmask6(2, 4)>(tot);
    res[3] = wave_red<rowmask6(3, 4)>(tot);
    res[4] = wave_red<rowmask6(4, 4)>(tot);
    res[5] = wave_red<rowmask6(5, 4)>(tot);
    #pragma unroll
    for (int j = 0; j < 6; ++j) res[6 + j] = wave_red<0>(Dq[j]);  // reg qubits

    float myres = res[0];
    #pragma unroll
    for (int q = 1; q < NQ; ++q) myres = (lane == q) ? res[q] : myres;
    myres *= G * G;
    if (lane < NQ) out[b * NQ + lane] = myres;
}

extern "C" void kernel_launch(void* const* d_in, const int* in_sizes, int n_in,
                              void* d_out, int out_size, void* d_ws, size_t ws_size,
                              hipStream_t stream) {
    const float* x     = (const float*)d_in[0];
    const float* theta = (const float*)d_in[1];
    float* out = (float*)d_out;
    dim3 grid(BATCH / 2), block(128);
    qc_kernel<<<grid, block, 0, stream>>>(x, theta, out);
}